// Round 2
// baseline (366.774 us; speedup 1.0000x reference)
//
#include <hip/hip_runtime.h>
#include <hip/hip_bf16.h>

typedef __attribute__((ext_vector_type(8))) short short8;
typedef __attribute__((ext_vector_type(4))) float float4v;
typedef __attribute__((ext_vector_type(2))) float float2v;
typedef __attribute__((ext_vector_type(4))) unsigned int uint4v;

#define NSAMP 10000
#define CIN   64
#define TLEN  64
#define COUT  64     // channels after GLU
#define TOUT  62
#define SPB   4      // samples per block
#define NBLK  (NSAMP / SPB)

// fp32 -> bf16 bits, round-to-nearest-even (inputs are never NaN/Inf)
static __device__ __forceinline__ ushort f2bf(float v) {
    unsigned int x = __float_as_uint(v);
    return (ushort)((x + 0x7fffu + ((x >> 16) & 1u)) >> 16);
}

// packed fp32x2 -> bf16x2 (lo = a, hi = b), RNE
static __device__ __forceinline__ unsigned int cvt_pk_bf16(float a, float b) {
    unsigned int r;
    asm("v_cvt_pk_bf16_f32 %0, %1, %2" : "=v"(r) : "v"(a), "v"(b));
    return r;
}

// Pre-permute + downconvert weights: Wa[co][kk], kk = k*64 + ci (bf16 bits).
// src: float w[co][ci][k] (strides 192, 3, 1)
__global__ void prep_weights(const float* __restrict__ w, ushort* __restrict__ wa) {
    int o = blockIdx.x * blockDim.x + threadIdx.x;
    if (o >= 128 * 192) return;
    int co = o / 192;
    int kk = o - co * 192;
    int k  = kk >> 6;
    int ci = kk & 63;
    wa[o] = f2bf(w[co * 192 + ci * 3 + k]);
}

// issue 8 coalesced dwordx2 loads for one sample's staging slice
static __device__ __forceinline__ void issue8(float2v (&dst)[8], const float* p) {
#pragma unroll
    for (int j = 0; j < 8; ++j)
        dst[j] = *(const float2v*)(p + j * TLEN);
}

// 4 waves: (w&1) = co-half, (w>>1) = t-half. Wave (h, nh): co in
// [32h,32h+32) U [32h+64,32h+96) (GLU pairs in-wave), t in [32nh, 32nh+32).
//
// Block processes SPB=4 samples. A-fragments (bf16 weights) live in
// registers for the whole block. x staging is double-buffered in LDS with
// depth-2 register prefetch; barriers are raw s_barrier + lgkmcnt(0) only,
// so prefetch loads stay in flight across them (no vmcnt(0) drain).
// LDS layout: bf16 [t][ci], 128B rows, XOR swizzle byte ^= ((t&7)<<4).
__global__ __launch_bounds__(256, 2)
void conv_glu(const float* __restrict__ x, const ushort* __restrict__ wa,
              const float* __restrict__ bias, float* __restrict__ out) {
    __shared__ __align__(16) ushort xT[2][64 * 64];   // 2 x 8 KB

    const int tid = threadIdx.x;
    const int w   = tid >> 6;      // wave id 0..3
    const int L   = tid & 63;      // lane
    const int l   = L & 15;
    const int q   = L >> 4;        // quad
    const int h   = w & 1;         // M half
    const int nh  = w >> 1;        // N half
    const int t0base = nh * 32;
    const int n0  = blockIdx.x * SPB;

    // staging decomposition: thread owns ci in [8*c8, 8*c8+8) x t in {2*t2, 2*t2+1}
    const int t2 = tid & 31;
    const int c8 = tid >> 5;
    const float* xs0 = x + (long)n0 * (CIN * TLEN) + c8 * 8 * TLEN + 2 * t2;

    // A fragments in registers for the whole block (96 VGPR).
    // A[m=lane&15][k=q*8+j]; row co, kk = kc*32 + q*8 + j.
    short8 afr[4][6];
#pragma unroll
    for (int mt = 0; mt < 4; ++mt) {
        int co = 32 * h + 16 * (mt & 1) + 64 * (mt >> 1) + l;
        const short8* wrow = (const short8*)(wa + co * 192);
#pragma unroll
        for (int kc = 0; kc < 6; ++kc)
            afr[mt][kc] = wrow[kc * 4 + q];
    }

    // bias preload (16 VGPR)
    float bv[2][4], bg[2][4];
#pragma unroll
    for (int p2 = 0; p2 < 2; ++p2)
#pragma unroll
        for (int r = 0; r < 4; ++r) {
            int co = 32 * h + 16 * p2 + 4 * q + r;
            bv[p2][r] = bias[co];
            bg[p2][r] = bias[co + 64];
        }

    // depth-2 prefetch register sets (rotating mod 3; all indices constant
    // after full unroll, so these stay in registers)
    float2v ld[3][8];
    issue8(ld[0], xs0);
    issue8(ld[1], xs0 + CIN * TLEN);

#pragma unroll
    for (int s = 0; s < SPB; ++s) {
        if (s + 2 < SPB)
            issue8(ld[(s + 2) % 3], xs0 + (long)(s + 2) * (CIN * TLEN));

        // ---- cvt + swizzled ds_write_b128 into xT[s&1] ----
        // (compiler inserts the precise vmcnt wait for ld[s%3] here)
        {
            char* base = (char*)xT[s & 1];
#pragma unroll
            for (int r = 0; r < 2; ++r) {
                int t = 2 * t2 + r;
                uint4v val;
#pragma unroll
                for (int k2 = 0; k2 < 4; ++k2)
                    val[k2] = cvt_pk_bf16(ld[s % 3][2 * k2][r],
                                          ld[s % 3][2 * k2 + 1][r]);
                *(uint4v*)(base + t * 128 + ((c8 * 16) ^ ((t & 7) << 4))) = val;
            }
        }

        // barrier WITHOUT vmcnt drain: LDS writes visible, prefetch stays in flight
        asm volatile("s_waitcnt lgkmcnt(0)" ::: "memory");
        __builtin_amdgcn_s_barrier();

        // ---- K loop on xT[s&1] ----
        float4v acc[4][2];
#pragma unroll
        for (int mt = 0; mt < 4; ++mt)
#pragma unroll
            for (int nt = 0; nt < 2; ++nt)
                acc[mt][nt] = (float4v){0.f, 0.f, 0.f, 0.f};

        const char* rbase = (const char*)xT[s & 1];
#pragma unroll
        for (int kc = 0; kc < 6; ++kc) {
            const int tap  = kc >> 1;
            const int cib2 = (kc & 1) * 64 + q * 16;   // byte offset of ci-slice
#pragma unroll
            for (int nt = 0; nt < 2; ++nt) {
                int t = t0base + nt * 16 + l + tap;
                if (t > 63) t = 63;                    // pad cols (t>=62 discarded)
                const short8 bfr = *(const short8*)(rbase + t * 128
                                                    + (cib2 ^ ((t & 7) << 4)));
#pragma unroll
                for (int mt = 0; mt < 4; ++mt)
                    acc[mt][nt] = __builtin_amdgcn_mfma_f32_16x16x32_bf16(
                        afr[mt][kc], bfr, acc[mt][nt], 0, 0, 0);
            }
        }

        // ---- epilogue: bias + GLU, nontemporal fp32 stores ----
        float* outn = out + (long)(n0 + s) * (COUT * TOUT);
#pragma unroll
        for (int p2 = 0; p2 < 2; ++p2)
#pragma unroll
            for (int nt = 0; nt < 2; ++nt)
#pragma unroll
                for (int r = 0; r < 4; ++r) {
                    int co = 32 * h + 16 * p2 + 4 * q + r;
                    int t  = t0base + nt * 16 + l;
                    float a = acc[p2][nt][r]     + bv[p2][r];
                    float g = acc[p2 + 2][nt][r] + bg[p2][r];
                    float sg = 1.0f / (1.0f + __expf(-g));
                    if (t < TOUT)
                        __builtin_nontemporal_store(a * sg, &outn[co * TOUT + t]);
                }
        // no trailing barrier: next iteration writes the OTHER LDS buffer,
        // whose last readers finished before the barrier above (hazard chain:
        // read(s-1) < bar(s) < write(s+1), same buffer two apart).
    }
}

extern "C" void kernel_launch(void* const* d_in, const int* in_sizes, int n_in,
                              void* d_out, int out_size, void* d_ws, size_t ws_size,
                              hipStream_t stream) {
    const float* x    = (const float*)d_in[0];
    const float* wt   = (const float*)d_in[1];
    const float* bias = (const float*)d_in[2];
    ushort*      wa   = (ushort*)d_ws;        // 48 KB permuted bf16 weights
    float*       out  = (float*)d_out;

    prep_weights<<<96, 256, 0, stream>>>(wt, wa);
    conv_glu<<<NBLK, 256, 0, stream>>>(x, wa, bias, out);
}